// Round 6
// baseline (102.560 us; speedup 1.0000x reference)
//
#include <hip/hip_runtime.h>

// Problem dims (fixed by reference): x shape (2,4,8,256,256) f32
#define WD 256
#define HT 256
#define DP 8
#define NBC 8
#define HW 65536       // HT*WD
#define DHW 524288     // DP*HW
#define NVOX 4194304   // NBC*DHW

typedef float f32x4 __attribute__((ext_vector_type(4)));

__device__ __forceinline__ f32x4 ld4(const float* p) { return *(const f32x4*)p; }
__device__ __forceinline__ void st4_nt(float* p, f32x4 v) {
    __builtin_nontemporal_store(v, (f32x4*)p);
}

// Cramer 3x3 symmetric solve — transcribed 1:1 from the reference,
// contraction off to track numpy bit-closely.
__device__ __forceinline__ bool solve3(float dxx, float dyy, float dss,
                                       float dxy, float dxs, float dys,
                                       float gx, float gy, float gs,
                                       float& sx, float& sy, float& ss) {
#pragma clang fp contract(off)
    float r0 = -gx, r1 = -gy, r2 = -gs;
    float cf00 = dyy * dss - dys * dys;
    float cf01 = dxy * dss - dys * dxs;
    float cf02 = dxy * dys - dyy * dxs;
    float det = dxx * cf00 - dxy * cf01 + dxs * cf02;
    bool solved = fabsf(det) > 0.0f;
    float sdet = solved ? det : 1.0f;
    sx = (r0 * cf00 - dxy * (r1 * dss - dys * r2) + dxs * (r1 * dys - dyy * r2)) / sdet;
    sy = (dxx * (r1 * dss - dys * r2) - r0 * cf01 + dxs * (dxy * r2 - r1 * dxs)) / sdet;
    ss = (dxx * (dyy * r2 - r1 * dys) - dxy * (dxy * r2 - r1 * dxs) + r0 * cf02) / sdet;
    return solved;
}

// Iterations 1..4 of the reference loop (memory taps; iter 0 was done from
// registers by the caller). Entered only when still valid and moved.
// Updates d,h,w,shifts,gds in place; returns final validity.
__device__ bool refine_cont(const float* __restrict__ xb,
                            int& d, int& h, int& w,
                            float& shx, float& shy, float& shs, float& gds) {
#pragma clang fp contract(off)
    bool valid = true;
    for (int it = 1; it < 5; ++it) {
        int dcl = min(max(d, 1), DP - 2);
        int hcl = min(max(h, 1), HT - 2);
        int wcl = min(max(w, 1), WD - 2);
        const float* q = xb + dcl * HW + hcl * WD + wcl;
        float c000 = q[0];
        float pxm = q[-1],  pxp = q[1];
        float pym = q[-WD], pyp = q[WD];
        float psm = q[-HW], psp = q[HW];
        float gx = 0.5f * (pxp - pxm);
        float gy = 0.5f * (pyp - pym);
        float gs = 0.5f * (psp - psm);
        float dxx = pxp - 2.0f * c000 + pxm;
        float dyy = pyp - 2.0f * c000 + pym;
        float dss = psp - 2.0f * c000 + psm;
        float dxy = 0.25f * (q[WD + 1]  - q[WD - 1]  - q[-WD + 1]  + q[-WD - 1]);
        float dxs = 0.25f * (q[HW + 1]  - q[HW - 1]  - q[-HW + 1]  + q[-HW - 1]);
        float dys = 0.25f * (q[HW + WD] - q[HW - WD] - q[-HW + WD] + q[-HW - WD]);
        float sx, sy, ss;
        bool solved = solve3(dxx, dyy, dss, dxy, dxs, dys, gx, gy, gs, sx, sy, ss);
        valid = valid && solved;
        if (valid) {
            shx = sx; shy = sy; shs = ss;
            gds = gx * sx + gy * sy + gs * ss;
        } else {
            sx = 0.f; sy = 0.f; ss = 0.f;
        }
        int mvx = (valid && sx > 0.6f) ? 1 : ((valid && sx < -0.6f) ? -1 : 0);
        int nw = w + mvx;
        valid = valid && (nw >= 1) && (nw <= WD - 2);
        w = min(max(nw, 0), WD - 1);
        int mvy = (valid && sy > 0.6f) ? 1 : ((valid && sy < -0.6f) ? -1 : 0);
        int nh = h + mvy;
        valid = valid && (nh >= 1) && (nh <= HT - 2);
        h = min(max(nh, 0), HT - 1);
        int mvd = (valid && ss > 0.6f) ? 1 : ((valid && ss < -0.6f) ? -1 : 0);
        int nd = d + mvd;
        valid = valid && (nd >= 1) && (nd <= DP - 2);
        d = min(max(nd, 0), DP - 1);
        if (!valid) break;
        if (mvx == 0 && mvy == 0 && mvd == 0) break;
    }
    return valid && (fabsf(shx) <= 1.5f) && (fabsf(shy) <= 1.5f) && (fabsf(shs) <= 1.5f);
}

// Single fused kernel: one thread per 4 w-consecutive voxels.
// - NMS from 9 row-float4 loads + L/R shuffles (as round 2, verified).
// - Refine iteration 1 computed ENTIRELY from the registers already loaded
//   for NMS (zero memory taps); memory loop only for the rare movers.
// - Outputs composed in registers, each address written exactly once,
//   nontemporal (outputs are never re-read; keeps L2 for the input rows).
__global__ __launch_bounds__(256, 4) void fused(const float* __restrict__ x,
                                                float* __restrict__ out) {
#pragma clang fp contract(off)
    int t = blockIdx.x * 256 + threadIdx.x;   // [0, NVOX/4)
    int lane = t & 63;
    int w0 = lane << 2;
    int h  = (t >> 6) & 255;
    int d  = (t >> 14) & 7;
    int bc = t >> 17;
    size_t pos = (size_t)d * HW + (size_t)h * WD + (size_t)w0;
    const float* xb = x + (size_t)bc * DHW;
    const float* rowc = xb + pos;
    f32x4 c = ld4(rowc);

    float fd = (float)d, fh = (float)h, fw = (float)w0;
    float* yb = out + (size_t)NBC * 3 * DHW + (size_t)bc * DHW + pos;
    float* cb = out + (size_t)(bc * 3) * DHW + pos;
    f32x4 ocs = {fd, fd, fd, fd};
    f32x4 ocx = {fw, fw + 1.f, fw + 2.f, fw + 3.f};
    f32x4 ocy = {fh, fh, fh, fh};
    f32x4 oy  = c;

    // border rows can never be strict maxima (edge-replicated padding);
    // wave-uniform exit (one wave == one (bc,d,h) row).
    if (d == 0 || d == DP - 1 || h == 0 || h == HT - 1) {
        st4_nt(cb, ocs); st4_nt(cb + DHW, ocx); st4_nt(cb + 2 * DHW, ocy); st4_nt(yb, oy);
        return;
    }

    // 9 neighborhood rows: r{d}{h}, m/0/p = -1/0/+1 offset.
    f32x4 rmm = ld4(rowc - HW - WD);
    f32x4 rm0 = ld4(rowc - HW);
    f32x4 rmp = ld4(rowc - HW + WD);
    f32x4 r0m = ld4(rowc - WD);
    f32x4 r00 = c;
    f32x4 r0p = ld4(rowc + WD);
    f32x4 rpm = ld4(rowc + HW - WD);
    f32x4 rp0 = ld4(rowc + HW);
    f32x4 rpp = ld4(rowc + HW + WD);

    // L (x[w0-1]) / R (x[w0+4]) per row via wave shuffles (whole wave active).
    float Lmm = __shfl_up(rmm.w, 1), Rmm = __shfl_down(rmm.x, 1);
    float Lm0 = __shfl_up(rm0.w, 1), Rm0 = __shfl_down(rm0.x, 1);
    float Lmp = __shfl_up(rmp.w, 1), Rmp = __shfl_down(rmp.x, 1);
    float L0m = __shfl_up(r0m.w, 1), R0m = __shfl_down(r0m.x, 1);
    float L00 = __shfl_up(r00.w, 1), R00 = __shfl_down(r00.x, 1);
    float L0p = __shfl_up(r0p.w, 1), R0p = __shfl_down(r0p.x, 1);
    float Lpm = __shfl_up(rpm.w, 1), Rpm = __shfl_down(rpm.x, 1);
    float Lp0 = __shfl_up(rp0.w, 1), Rp0 = __shfl_down(rp0.x, 1);
    float Lpp = __shfl_up(rpp.w, 1), Rpp = __shfl_down(rpp.x, 1);

    const float NEG = -3.4e38f;
    float n0 = NEG, n1 = NEG, n2 = NEG, n3 = NEG;
#define ACC(vv, LL, RR)                                  \
    n0 = fmaxf(n0, fmaxf(fmaxf(LL, vv.x), vv.y));        \
    n1 = fmaxf(n1, fmaxf(fmaxf(vv.x, vv.y), vv.z));      \
    n2 = fmaxf(n2, fmaxf(fmaxf(vv.y, vv.z), vv.w));      \
    n3 = fmaxf(n3, fmaxf(fmaxf(vv.z, vv.w), RR));
    ACC(rmm, Lmm, Rmm) ACC(rm0, Lm0, Rm0) ACC(rmp, Lmp, Rmp)
    ACC(r0m, L0m, R0m)                    ACC(r0p, L0p, R0p)
    ACC(rpm, Lpm, Rpm) ACC(rp0, Lp0, Rp0) ACC(rpp, Lpp, Rpp)
#undef ACC
    // center row: exclude the center element itself
    n0 = fmaxf(n0, fmaxf(L00,   r00.y));
    n1 = fmaxf(n1, fmaxf(r00.x, r00.z));
    n2 = fmaxf(n2, fmaxf(r00.y, r00.w));
    n3 = fmaxf(n3, fmaxf(r00.z, R00));

    bool m0 = (c.x > n0) && (w0 > 0);          // w=0 never a max
    bool m1 = (c.y > n1);
    bool m2 = (c.z > n2);
    bool m3 = (c.w > n3) && (w0 + 3 < WD - 1); // w=255 never a max
    unsigned mbits = (m0 ? 1u : 0u) | (m1 ? 2u : 0u) | (m2 ? 4u : 0u) | (m3 ? 8u : 0u);

    if (mbits) {
        // element-i selection from a row's {L, v.xyzw, R} span (w0-1 .. w0+4)
#define SEL3(row, LL, RR, am1, a0, ap1)                                          \
        am1 = (i == 0) ? LL    : ((i == 1) ? row.x : ((i == 2) ? row.y : row.z)); \
        a0  = (i == 0) ? row.x : ((i == 1) ? row.y : ((i == 2) ? row.z : row.w)); \
        ap1 = (i == 0) ? row.y : ((i == 1) ? row.z : ((i == 2) ? row.w : RR));
#define SEL0(row) ((i == 0) ? row.x : ((i == 1) ? row.y : ((i == 2) ? row.z : row.w)))
        unsigned mb = mbits;
        while (mb) {
            int i = __ffs(mb) - 1;
            mb &= mb - 1;
            float pxm, c000, pxp;          SEL3(r00, L00, R00, pxm, c000, pxp);
            float ym_m1, ym_0, ym_p1;      SEL3(r0m, L0m, R0m, ym_m1, ym_0, ym_p1);
            float yp_m1, yp_0, yp_p1;      SEL3(r0p, L0p, R0p, yp_m1, yp_0, yp_p1);
            float sm_m1, sm_0, sm_p1;      SEL3(rm0, Lm0, Rm0, sm_m1, sm_0, sm_p1);
            float sp_m1, sp_0, sp_p1;      SEL3(rp0, Lp0, Rp0, sp_m1, sp_0, sp_p1);
            float gx = 0.5f * (pxp - pxm);
            float gy = 0.5f * (yp_0 - ym_0);
            float gs = 0.5f * (sp_0 - sm_0);
            float dxx = pxp - 2.0f * c000 + pxm;
            float dyy = yp_0 - 2.0f * c000 + ym_0;
            float dss = sp_0 - 2.0f * c000 + sm_0;
            float dxy = 0.25f * (yp_p1 - yp_m1 - ym_p1 + ym_m1);
            float dxs = 0.25f * (sp_p1 - sp_m1 - sm_p1 + sm_m1);
            float dys = 0.25f * (SEL0(rpp) - SEL0(rpm) - SEL0(rmp) + SEL0(rmm));
            float sx, sy, ss;
            bool valid = solve3(dxx, dyy, dss, dxy, dxs, dys, gx, gy, gs, sx, sy, ss);
            if (valid) {
                float shx = sx, shy = sy, shs = ss;
                float gds = gx * sx + gy * sy + gs * ss;
                int w = w0 + i, hh = h, dd = d;
                // iteration-1 move/bounds updates (positions are interior,
                // clamps are no-ops; exact reference ordering of valid)
                int mvx = (sx > 0.6f) ? 1 : ((sx < -0.6f) ? -1 : 0);
                int nw = w + mvx;
                bool v2 = (nw >= 1) && (nw <= WD - 2);
                w = min(max(nw, 0), WD - 1);
                int mvy = v2 ? ((sy > 0.6f) ? 1 : ((sy < -0.6f) ? -1 : 0)) : 0;
                int nh = hh + mvy;
                v2 = v2 && (nh >= 1) && (nh <= HT - 2);
                hh = min(max(nh, 0), HT - 1);
                int mvd = v2 ? ((ss > 0.6f) ? 1 : ((ss < -0.6f) ? -1 : 0)) : 0;
                int nd = dd + mvd;
                v2 = v2 && (nd >= 1) && (nd <= DP - 2);
                dd = min(max(nd, 0), DP - 1);
                bool wr = false;
                float fs = 0.f, fx = 0.f, fy = 0.f, yv = 0.f;
                if (v2) {
                    if (mvx == 0 && mvy == 0 && mvd == 0) {
                        // fixed point: remaining iterations are identical;
                        // |s*| <= 0.6 so the final 1.5-checks pass.
                        wr = true;
                        fs = (float)dd + shs; fx = (float)w + shx; fy = (float)hh + shy;
                        yv = c000 + 0.5f * gds + 10.0f;
                    } else {
                        bool ok = refine_cont(xb, dd, hh, w, shx, shy, shs, gds);
                        if (ok) {
                            wr = true;
                            fs = (float)dd + shs; fx = (float)w + shx; fy = (float)hh + shy;
                            yv = c000 + 0.5f * gds + 10.0f;
                        }
                    }
                }
                if (wr) {
                    if      (i == 0) { ocs.x = fs; ocx.x = fx; ocy.x = fy; oy.x = yv; }
                    else if (i == 1) { ocs.y = fs; ocx.y = fx; ocy.y = fy; oy.y = yv; }
                    else if (i == 2) { ocs.z = fs; ocx.z = fx; ocy.z = fy; oy.z = yv; }
                    else             { ocs.w = fs; ocx.w = fx; ocy.w = fy; oy.w = yv; }
                }
            }
        }
#undef SEL3
#undef SEL0
    }

    st4_nt(cb, ocs); st4_nt(cb + DHW, ocx); st4_nt(cb + 2 * DHW, ocy); st4_nt(yb, oy);
}

extern "C" void kernel_launch(void* const* d_in, const int* in_sizes, int n_in,
                              void* d_out, int out_size, void* d_ws, size_t ws_size,
                              hipStream_t stream) {
    const float* x = (const float*)d_in[0];
    float* out = (float*)d_out;
    (void)d_ws; (void)ws_size;
    fused<<<NVOX / 4 / 256, 256, 0, stream>>>(x, out);
}

// Round 7
// 97.447 us; speedup vs baseline: 1.0525x; 1.0525x over previous
//
#include <hip/hip_runtime.h>

// Problem dims (fixed by reference): x shape (2,4,8,256,256) f32
#define WD 256
#define HT 256
#define DP 8
#define NBC 8
#define HW 65536       // HT*WD
#define DHW 524288     // DP*HW
#define NVOX 4194304   // NBC*DHW
#define NBLK (NVOX / 4 / 256)   // 16384 blocks
#define NXCD 8

// Full quadratic-interp refinement for one masked voxel; overwrites the
// 4 output scalars if the final 'valid' is true (defaults already written
// by the caller otherwise). Math transcribed 1:1 from the reference; fp
// contraction off to track the numpy reference bit-closely.
__device__ void refine_write(const float* __restrict__ x,
                             float* __restrict__ out,
                             int idx) {
#pragma clang fp contract(off)
    const int w0 = idx & 255;
    const int h0 = (idx >> 8) & 255;
    const int d0 = (idx >> 16) & 7;
    const int bc = idx >> 19;
    int d = d0, h = h0, w = w0;
    bool valid = true;
    float shx = 0.f, shy = 0.f, shs = 0.f, gds = 0.f;
    const float* xb = x + (size_t)bc * DHW;
    for (int it = 0; it < 5; ++it) {
        int dcl = min(max(d, 1), DP - 2);
        int hcl = min(max(h, 1), HT - 2);
        int wcl = min(max(w, 1), WD - 2);
        const float* q = xb + dcl * HW + hcl * WD + wcl;
        float c000 = q[0];
        float pxm = q[-1],   pxp = q[1];
        float pym = q[-WD],  pyp = q[WD];
        float psm = q[-HW],  psp = q[HW];
        float gx = 0.5f * (pxp - pxm);
        float gy = 0.5f * (pyp - pym);
        float gs = 0.5f * (psp - psm);
        float dxx = pxp - 2.0f * c000 + pxm;
        float dyy = pyp - 2.0f * c000 + pym;
        float dss = psp - 2.0f * c000 + psm;
        float dxy = 0.25f * (q[WD + 1]  - q[WD - 1]  - q[-WD + 1]  + q[-WD - 1]);
        float dxs = 0.25f * (q[HW + 1]  - q[HW - 1]  - q[-HW + 1]  + q[-HW - 1]);
        float dys = 0.25f * (q[HW + WD] - q[HW - WD] - q[-HW + WD] + q[-HW - WD]);
        float r0 = -gx, r1 = -gy, r2 = -gs;
        float cf00 = dyy * dss - dys * dys;
        float cf01 = dxy * dss - dys * dxs;
        float cf02 = dxy * dys - dyy * dxs;
        float det = dxx * cf00 - dxy * cf01 + dxs * cf02;
        bool solved = fabsf(det) > 0.0f;
        float sdet = solved ? det : 1.0f;
        float sx = (r0 * cf00 - dxy * (r1 * dss - dys * r2) + dxs * (r1 * dys - dyy * r2)) / sdet;
        float sy = (dxx * (r1 * dss - dys * r2) - r0 * cf01 + dxs * (dxy * r2 - r1 * dxs)) / sdet;
        float ss = (dxx * (dyy * r2 - r1 * dys) - dxy * (dxy * r2 - r1 * dxs) + r0 * cf02) / sdet;
        valid = valid && solved;
        if (valid) {
            shx = sx; shy = sy; shs = ss;
            gds = gx * sx + gy * sy + gs * ss;
        } else {
            sx = 0.f; sy = 0.f; ss = 0.f;
        }
        int mvx = (valid && sx > 0.6f) ? 1 : ((valid && sx < -0.6f) ? -1 : 0);
        int nw = w + mvx;
        valid = valid && (nw >= 1) && (nw <= WD - 2);
        w = min(max(nw, 0), WD - 1);
        int mvy = (valid && sy > 0.6f) ? 1 : ((valid && sy < -0.6f) ? -1 : 0);
        int nh = h + mvy;
        valid = valid && (nh >= 1) && (nh <= HT - 2);
        h = min(max(nh, 0), HT - 1);
        int mvd = (valid && ss > 0.6f) ? 1 : ((valid && ss < -0.6f) ? -1 : 0);
        int nd = d + mvd;
        valid = valid && (nd >= 1) && (nd <= DP - 2);
        d = min(max(nd, 0), DP - 1);
        if (!valid) break;                    // state can no longer change
        if (mvx == 0 && mvy == 0 && mvd == 0) // fixed point: identical iterations follow
            break;
    }
    valid = valid && (fabsf(shx) <= 1.5f) && (fabsf(shy) <= 1.5f) && (fabsf(shs) <= 1.5f);
    if (!valid) return; // defaults are the correct output

    size_t pos = (size_t)d0 * HW + (size_t)h0 * WD + (size_t)w0;
    float* cb = out + (size_t)(bc * 3) * DHW + pos;
    cb[0]         = (float)d + shs;
    cb[DHW]       = (float)w + shx;
    cb[2 * DHW]   = (float)h + shy;
    float corr = 0.5f * gds + 10.0f;
    float* yb = out + (size_t)NBC * 3 * DHW;
    yb[(size_t)bc * DHW + pos] = x[idx] + corr;
}

// Single fused pass (round-2 structure, verified absmax 0.0) + T1 XCD swizzle:
// blockIdx round-robins across the 8 XCD L2s, so h/d-neighbor blocks (which
// re-read the same input rows 3x3=9 ways) land on DIFFERENT XCDs and the
// 151MB of logical stencil re-reads get served by LLC, not the 4MB XCD-L2.
// Remap so each XCD owns a contiguous 2048-block chunk (= 32 (bc,d) slabs;
// h-reuse distance 1KB, d-reuse 256KB, both << 4MB L2).
__global__ __launch_bounds__(256) void fused(const float* __restrict__ x,
                                             float* __restrict__ out) {
    // bijective XCD swizzle (NBLK % NXCD == 0)
    int vb = (blockIdx.x % NXCD) * (NBLK / NXCD) + blockIdx.x / NXCD;
    int t = vb * 256 + threadIdx.x;           // [0, NVOX/4)
    int lane = t & 63;
    int w0 = lane << 2;
    int h  = (t >> 6) & 255;
    int d  = (t >> 14) & 7;
    int bc = t >> 17;
    size_t pos = (size_t)d * HW + (size_t)h * WD + (size_t)w0;
    const float* xb = x + (size_t)bc * DHW;
    float4 c = *(const float4*)(xb + pos);

    // defaults: y = x ; coords = (d, w, h)
    float* yb = out + (size_t)NBC * 3 * DHW;
    *(float4*)(yb + (size_t)bc * DHW + pos) = c;
    float* cb = out + (size_t)(bc * 3) * DHW + pos;
    float fd = (float)d, fh = (float)h, fw = (float)w0;
    *(float4*)(cb)           = make_float4(fd, fd, fd, fd);
    *(float4*)(cb + DHW)     = make_float4(fw, fw + 1.f, fw + 2.f, fw + 3.f);
    *(float4*)(cb + 2 * DHW) = make_float4(fh, fh, fh, fh);

    // border rows can never be strict maxima (edge-replicated padding);
    // d,h are wave-uniform (one wave == one row) so this exit keeps full
    // wave participation for the shuffles below.
    if (d == 0 || d == DP - 1 || h == 0 || h == HT - 1) return;

    const float NEG = -3.4e38f;
    float n0 = NEG, n1 = NEG, n2 = NEG, n3 = NEG;
    const float* rowc = xb + pos;
#pragma unroll
    for (int dd = -1; dd <= 1; ++dd) {
#pragma unroll
        for (int hh = -1; hh <= 1; ++hh) {
            float4 v;
            if (dd == 0 && hh == 0) v = c;
            else v = *(const float4*)(rowc + dd * HW + hh * WD);
            float L = __shfl_up(v.w, 1);   // lane-1's last elem = x[w0-1]
            float R = __shfl_down(v.x, 1); // lane+1's first elem = x[w0+4]
            if (dd == 0 && hh == 0) {
                // center row: exclude the center element itself
                n0 = fmaxf(n0, fmaxf(L,   v.y));
                n1 = fmaxf(n1, fmaxf(v.x, v.z));
                n2 = fmaxf(n2, fmaxf(v.y, v.w));
                n3 = fmaxf(n3, fmaxf(v.z, R));
            } else {
                n0 = fmaxf(n0, fmaxf(fmaxf(L,   v.x), v.y));
                n1 = fmaxf(n1, fmaxf(fmaxf(v.x, v.y), v.z));
                n2 = fmaxf(n2, fmaxf(fmaxf(v.y, v.z), v.w));
                n3 = fmaxf(n3, fmaxf(fmaxf(v.z, v.w), R));
            }
        }
    }
    bool m0 = (c.x > n0) && (w0 > 0);            // w=0 never a max (lane 0 L garbage is fine)
    bool m1 = (c.y > n1);
    bool m2 = (c.z > n2);
    bool m3 = (c.w > n3) && (w0 + 3 < WD - 1);   // w=255 never a max
    unsigned mbits = (m0 ? 1u : 0u) | (m1 ? 2u : 0u) | (m2 ? 4u : 0u) | (m3 ? 8u : 0u);
    if (!mbits) return;
    int vidx = (bc << 19) | (d << 16) | (h << 8) | w0;
    while (mbits) {
        int i = __ffs(mbits) - 1;
        mbits &= mbits - 1;
        refine_write(x, out, vidx + i);
    }
}

extern "C" void kernel_launch(void* const* d_in, const int* in_sizes, int n_in,
                              void* d_out, int out_size, void* d_ws, size_t ws_size,
                              hipStream_t stream) {
    const float* x = (const float*)d_in[0];
    float* out = (float*)d_out;
    (void)d_ws; (void)ws_size;
    fused<<<NBLK, 256, 0, stream>>>(x, out);
}

// Round 8
// 95.454 us; speedup vs baseline: 1.0744x; 1.0209x over previous
//
#include <hip/hip_runtime.h>

// Problem dims (fixed by reference): x shape (2,4,8,256,256) f32
#define WD 256
#define HT 256
#define DP 8
#define NBC 8
#define HW 65536       // HT*WD
#define DHW 524288     // DP*HW
#define NVOX 4194304   // NBC*DHW

// Full quadratic-interp refinement for one masked voxel; overwrites the
// 4 output scalars if the final 'valid' is true (defaults already written
// by the caller otherwise). Math transcribed 1:1 from the reference; fp
// contraction off to track the numpy reference bit-closely.
// __noinline__: called from 4 unrolled sites; rare execution, keep I-size.
__device__ __attribute__((noinline)) void refine_write(const float* __restrict__ x,
                                                       float* __restrict__ out,
                                                       int idx) {
#pragma clang fp contract(off)
    const int w0 = idx & 255;
    const int h0 = (idx >> 8) & 255;
    const int d0 = (idx >> 16) & 7;
    const int bc = idx >> 19;
    int d = d0, h = h0, w = w0;
    bool valid = true;
    float shx = 0.f, shy = 0.f, shs = 0.f, gds = 0.f;
    const float* xb = x + (size_t)bc * DHW;
    for (int it = 0; it < 5; ++it) {
        int dcl = min(max(d, 1), DP - 2);
        int hcl = min(max(h, 1), HT - 2);
        int wcl = min(max(w, 1), WD - 2);
        const float* q = xb + dcl * HW + hcl * WD + wcl;
        float c000 = q[0];
        float pxm = q[-1],   pxp = q[1];
        float pym = q[-WD],  pyp = q[WD];
        float psm = q[-HW],  psp = q[HW];
        float gx = 0.5f * (pxp - pxm);
        float gy = 0.5f * (pyp - pym);
        float gs = 0.5f * (psp - psm);
        float dxx = pxp - 2.0f * c000 + pxm;
        float dyy = pyp - 2.0f * c000 + pym;
        float dss = psp - 2.0f * c000 + psm;
        float dxy = 0.25f * (q[WD + 1]  - q[WD - 1]  - q[-WD + 1]  + q[-WD - 1]);
        float dxs = 0.25f * (q[HW + 1]  - q[HW - 1]  - q[-HW + 1]  + q[-HW - 1]);
        float dys = 0.25f * (q[HW + WD] - q[HW - WD] - q[-HW + WD] + q[-HW - WD]);
        float r0 = -gx, r1 = -gy, r2 = -gs;
        float cf00 = dyy * dss - dys * dys;
        float cf01 = dxy * dss - dys * dxs;
        float cf02 = dxy * dys - dyy * dxs;
        float det = dxx * cf00 - dxy * cf01 + dxs * cf02;
        bool solved = fabsf(det) > 0.0f;
        float sdet = solved ? det : 1.0f;
        float sx = (r0 * cf00 - dxy * (r1 * dss - dys * r2) + dxs * (r1 * dys - dyy * r2)) / sdet;
        float sy = (dxx * (r1 * dss - dys * r2) - r0 * cf01 + dxs * (dxy * r2 - r1 * dxs)) / sdet;
        float ss = (dxx * (dyy * r2 - r1 * dys) - dxy * (dxy * r2 - r1 * dxs) + r0 * cf02) / sdet;
        valid = valid && solved;
        if (valid) {
            shx = sx; shy = sy; shs = ss;
            gds = gx * sx + gy * sy + gs * ss;
        } else {
            sx = 0.f; sy = 0.f; ss = 0.f;
        }
        int mvx = (valid && sx > 0.6f) ? 1 : ((valid && sx < -0.6f) ? -1 : 0);
        int nw = w + mvx;
        valid = valid && (nw >= 1) && (nw <= WD - 2);
        w = min(max(nw, 0), WD - 1);
        int mvy = (valid && sy > 0.6f) ? 1 : ((valid && sy < -0.6f) ? -1 : 0);
        int nh = h + mvy;
        valid = valid && (nh >= 1) && (nh <= HT - 2);
        h = min(max(nh, 0), HT - 1);
        int mvd = (valid && ss > 0.6f) ? 1 : ((valid && ss < -0.6f) ? -1 : 0);
        int nd = d + mvd;
        valid = valid && (nd >= 1) && (nd <= DP - 2);
        d = min(max(nd, 0), DP - 1);
        if (!valid) break;                    // state can no longer change
        if (mvx == 0 && mvy == 0 && mvd == 0) // fixed point: identical iterations follow
            break;
    }
    valid = valid && (fabsf(shx) <= 1.5f) && (fabsf(shy) <= 1.5f) && (fabsf(shs) <= 1.5f);
    if (!valid) return; // defaults are the correct output

    size_t pos = (size_t)d0 * HW + (size_t)h0 * WD + (size_t)w0;
    float* cb = out + (size_t)(bc * 3) * DHW + pos;
    cb[0]         = (float)d + shs;
    cb[DHW]       = (float)w + shx;
    cb[2 * DHW]   = (float)h + shy;
    float corr = 0.5f * gds + 10.0f;
    float* yb = out + (size_t)NBC * 3 * DHW;
    yb[(size_t)bc * DHW + pos] = x[idx] + corr;
}

struct Row { float4 v; float L, R; };

__device__ __forceinline__ Row load_row(const float* __restrict__ xb,
                                        int dd, int hh, int w0) {
    Row r;
    r.v = *(const float4*)(xb + (size_t)dd * HW + (size_t)hh * WD + w0);
    r.L = __shfl_up(r.v.w, 1);    // lane-1's last elem = x[w0-1]
    r.R = __shfl_down(r.v.x, 1);  // lane+1's first elem = x[w0+4]
    return r;
}

__device__ __forceinline__ void write_defaults(float* __restrict__ out,
                                               int bc, int d, int h, int w0,
                                               float4 c) {
    size_t pos = (size_t)d * HW + (size_t)h * WD + (size_t)w0;
    float* yb = out + (size_t)NBC * 3 * DHW + (size_t)bc * DHW + pos;
    *(float4*)yb = c;
    float* cb = out + (size_t)(bc * 3) * DHW + pos;
    float fd = (float)d, fh = (float)h, fw = (float)w0;
    *(float4*)(cb)           = make_float4(fd, fd, fd, fd);
    *(float4*)(cb + DHW)     = make_float4(fw, fw + 1.f, fw + 2.f, fw + 3.f);
    *(float4*)(cb + 2 * DHW) = make_float4(fh, fh, fh, fh);
}

// Register-carried row pipeline: each wave owns 4 consecutive h-rows of one
// (bc,d) slab. Rows (h-1,h,h+1)x3d overlap 6/9 with the next row's needs ->
// carry in registers (full unroll => SSA renaming, shifts are free).
// Loads/wave 36->18, DS shuffles 72->36, waves 16384->4096.
// Round-4 established NMS+defaults (not refine) is the entire cost over the
// BW floor; this attacks its instruction volume. Traffic unchanged.
__global__ __launch_bounds__(256) void fused(const float* __restrict__ x,
                                             float* __restrict__ out) {
    int lane = threadIdx.x & 63;
    int wib  = threadIdx.x >> 6;
    int g    = blockIdx.x * 4 + wib;   // wave id in [0, 4096)
    int q    = g & 63;                 // h-quad: rows q*4 .. q*4+3
    int slab = g >> 6;                 // bc*8 + d
    int d    = slab & 7;
    int bc   = slab >> 3;
    int w0   = lane << 2;
    const float* xb = x + (size_t)bc * DHW;
    int hbase = q << 2;

    if (d == 0 || d == DP - 1) {
        // whole 4-row run is a d-border: defaults only (never strict maxima)
#pragma unroll
        for (int k = 0; k < 4; ++k) {
            int h = hbase + k;
            float4 c = *(const float4*)(xb + (size_t)d * HW + (size_t)h * WD + w0);
            write_defaults(out, bc, d, h, w0, c);
        }
        return;
    }

    // pipeline state: {p,c,n} = h-1,h,h+1 ; {m,0,p} suffix = d-1,d,d+1
    Row pm, p0, pp, cm, c0, cp, nm, n0, np;
    bool primed = false;
    const float NEG = -3.4e38f;

#pragma unroll
    for (int k = 0; k < 4; ++k) {
        int h = hbase + k;
        if (h == 0) {                       // only k==0; not primed
            float4 c = *(const float4*)(xb + (size_t)h * WD + w0 + (size_t)d * HW);
            write_defaults(out, bc, d, h, w0, c);
            continue;
        }
        if (h == HT - 1) {                  // only k==3; primed (k==2 was interior)
            write_defaults(out, bc, d, h, w0, n0.v);
            continue;
        }
        if (!primed) {
            pm = load_row(xb, d - 1, h - 1, w0);
            p0 = load_row(xb, d,     h - 1, w0);
            pp = load_row(xb, d + 1, h - 1, w0);
            cm = load_row(xb, d - 1, h,     w0);
            c0 = load_row(xb, d,     h,     w0);
            cp = load_row(xb, d + 1, h,     w0);
            nm = load_row(xb, d - 1, h + 1, w0);
            n0 = load_row(xb, d,     h + 1, w0);
            np = load_row(xb, d + 1, h + 1, w0);
            primed = true;
        } else {
            pm = cm; p0 = c0; pp = cp;
            cm = nm; c0 = n0; cp = np;
            nm = load_row(xb, d - 1, h + 1, w0);
            n0 = load_row(xb, d,     h + 1, w0);
            np = load_row(xb, d + 1, h + 1, w0);
        }
        write_defaults(out, bc, d, h, w0, c0.v);

        float n0m = NEG, n1m = NEG, n2m = NEG, n3m = NEG;
#define ACC(rr)                                                    \
        n0m = fmaxf(n0m, fmaxf(fmaxf(rr.L,   rr.v.x), rr.v.y));    \
        n1m = fmaxf(n1m, fmaxf(fmaxf(rr.v.x, rr.v.y), rr.v.z));    \
        n2m = fmaxf(n2m, fmaxf(fmaxf(rr.v.y, rr.v.z), rr.v.w));    \
        n3m = fmaxf(n3m, fmaxf(fmaxf(rr.v.z, rr.v.w), rr.R));
        ACC(pm) ACC(p0) ACC(pp)
        ACC(cm)         ACC(cp)
        ACC(nm) ACC(n0) ACC(np)
#undef ACC
        // center row: exclude the center element itself
        n0m = fmaxf(n0m, fmaxf(c0.L,   c0.v.y));
        n1m = fmaxf(n1m, fmaxf(c0.v.x, c0.v.z));
        n2m = fmaxf(n2m, fmaxf(c0.v.y, c0.v.w));
        n3m = fmaxf(n3m, fmaxf(c0.v.z, c0.R));

        bool m0 = (c0.v.x > n0m) && (w0 > 0);          // w=0 never a max
        bool m1 = (c0.v.y > n1m);
        bool m2 = (c0.v.z > n2m);
        bool m3 = (c0.v.w > n3m) && (w0 + 3 < WD - 1); // w=255 never a max
        unsigned mbits = (m0 ? 1u : 0u) | (m1 ? 2u : 0u) | (m2 ? 4u : 0u) | (m3 ? 8u : 0u);
        if (mbits) {
            int vidx = (bc << 19) | (d << 16) | (h << 8) | w0;
            while (mbits) {
                int i = __ffs(mbits) - 1;
                mbits &= mbits - 1;
                refine_write(x, out, vidx + i);
            }
        }
    }
}

extern "C" void kernel_launch(void* const* d_in, const int* in_sizes, int n_in,
                              void* d_out, int out_size, void* d_ws, size_t ws_size,
                              hipStream_t stream) {
    const float* x = (const float*)d_in[0];
    float* out = (float*)d_out;
    (void)d_ws; (void)ws_size;
    fused<<<1024, 256, 0, stream>>>(x, out);
}